// Round 5
// baseline (316.198 us; speedup 1.0000x reference)
//
#include <hip/hip_runtime.h>
#include <math.h>

// Problem constants
#define NB 128     // batch
#define NC 128     // channels
#define NN 170     // nodes
#define NT 12      // length
#define MP 176     // padded row stride (16B-aligned rows) for xs/Es/Ed
#define BSROW 196  // LDS row stride for staged tiles (196%32==4 -> bank spread)

// Workspace regions (floats)
#define XS_SZ  (NB * NC * MP)   // 2,883,584
#define ESP_SZ (NC * MP)        //    22,528
#define ED_SZ  (NB * NN * MP)   // 3,829,760
#define PM_SZ  (NN * NN)        //    28,900

// tanh via hw exp+rcp: ~6 VALU ops vs ~30+ for libm tanhf. rel err ~1e-6.
__device__ __forceinline__ float fast_tanh(float x) {
    float cx = fminf(fmaxf(x, -15.f), 15.f);        // avoid inf/inf
    float e  = __expf(2.f * cx);                    // v_exp_f32
    return (e - 1.f) * __builtin_amdgcn_rcpf(e + 1.f);
}

// ---------------------------------------------------------------------------
// K1: three jobs, split by blockIdx range (all independent):
//   [0,10880)      xs[b][c][n] = sum_t x[..t], PADDED to stride 176 (zeros in
//                  cols >=170). Coalesced wave loads + 9 __shfl gathers.
//   [10880,10968)  Esp = Es padded to stride 176.
//   [10968,11081)  Pm zeroed (harness poisons ws to 0xAA; K3 atomically
//                  accumulates into Pm, so it must start at 0).
// ---------------------------------------------------------------------------
__global__ __launch_bounds__(256) void k1_reduce_pad(const float* __restrict__ x,
                                                     const float* __restrict__ Es,
                                                     float* __restrict__ xs,
                                                     float* __restrict__ Esp,
                                                     float* __restrict__ Pm) {
    if (blockIdx.x >= 10968) {              // Pm zero tail: 113 blocks
        int idx = (blockIdx.x - 10968) * 256 + threadIdx.x;
        if (idx < PM_SZ) Pm[idx] = 0.f;
        return;
    }
    if (blockIdx.x >= 10880) {              // Es padding tail: 88 blocks
        int idx = (blockIdx.x - 10880) * 256 + threadIdx.x;
        if (idx < ESP_SZ) {
            int c = idx / MP, m = idx % MP;
            Esp[idx] = (m < NN) ? Es[c * NN + m] : 0.f;
        }
        return;
    }
    const int w    = blockIdx.x * 4 + (threadIdx.x >> 6);  // global wave id
    const int lane = threadIdx.x & 63;
    const float4* x4 = reinterpret_cast<const float4*>(x) + (size_t)w * 192;
    float4 f0 = x4[lane], f1 = x4[lane + 64], f2 = x4[lane + 128];
    float p0 = (f0.x + f0.y) + (f0.z + f0.w);
    float p1 = (f1.x + f1.y) + (f1.z + f1.w);
    float p2 = (f2.x + f2.y) + (f2.z + f2.w);
    float tot = 0.f;
    #pragma unroll
    for (int j = 0; j < 3; ++j) {
        int s = 3 * lane + j;
        int src = s & 63, reg = s >> 6;
        float a0 = __shfl(p0, src, 64);
        float a1 = __shfl(p1, src, 64);
        float a2 = __shfl(p2, src, 64);
        tot += (reg == 0) ? a0 : (reg == 1) ? a1 : a2;
    }
    int g  = w * 64 + lane;                 // global group in [0, 2785280)
    int bc = g / NN, n = g - bc * NN;
    xs[(size_t)bc * MP + n] = tot;
    if (n < MP - NN) xs[(size_t)bc * MP + NN + n] = 0.f;   // zero the pad cols
}

// ---------------------------------------------------------------------------
// K2: Ed[b][n][m] = tanh( sum_c xs[b][c][n] * Esp[c][m] ), m in [0,176).
// Block = (b, 32-row tile): grid (6,128)=768 = 3 blocks/CU (12 waves/CU --
// measured better than the 48-row/2-blocks variant, R4 post-mortem).
// 256 threads as 16tx x 16ty; thread owns rows ty*2+{0,1}, cols
// tx*4 + off*64 (off<3; cols>=176 dropped). acc[2][12].
// ---------------------------------------------------------------------------
__global__ __launch_bounds__(256) void k2_embed(const float* __restrict__ xs,
                                                const float* __restrict__ Esp,
                                                float* __restrict__ Ed) {
    const int b = blockIdx.y, n0 = blockIdx.x * 32;
    const int t = threadIdx.x, tx = t & 15, ty = t >> 4;
    __shared__ __align__(16) float As[16][36];      // [c][n], 2.3 KB
    __shared__ __align__(16) float Bs[16][BSROW];   // [c][m], 12.5 KB

    float acc[2][12] = {};
    for (int c0 = 0; c0 < NC; c0 += 16) {
        __syncthreads();
        if (t < 128) {                               // A: 128 float4 (16c x 32n)
            int c = t >> 3, q = t & 7;
            float4 v = *reinterpret_cast<const float4*>(
                xs + ((size_t)(b * NC + c0 + c)) * MP + n0 + q * 4);
            *reinterpret_cast<float4*>(&As[c][q * 4]) = v;
        }
        #pragma unroll
        for (int it = 0; it < 3; ++it) {             // B: 768 float4 (16c x 192m)
            int idx = t + it * 256;
            int c = idx / 48, mq = idx - c * 48;
            float4 v = make_float4(0.f, 0.f, 0.f, 0.f);
            if (mq < 44)
                v = *reinterpret_cast<const float4*>(Esp + (c0 + c) * MP + mq * 4);
            *reinterpret_cast<float4*>(&Bs[c][mq * 4]) = v;
        }
        __syncthreads();
        #pragma unroll
        for (int cc = 0; cc < 16; ++cc) {
            float2 av = *reinterpret_cast<const float2*>(&As[cc][ty * 2]);
            float a[2] = {av.x, av.y};
            float bb[12];
            #pragma unroll
            for (int off = 0; off < 3; ++off) {
                float4 bv = *reinterpret_cast<const float4*>(&Bs[cc][tx * 4 + off * 64]);
                bb[off * 4 + 0] = bv.x; bb[off * 4 + 1] = bv.y;
                bb[off * 4 + 2] = bv.z; bb[off * 4 + 3] = bv.w;
            }
            #pragma unroll
            for (int ii = 0; ii < 2; ++ii)
                #pragma unroll
                for (int jj = 0; jj < 12; ++jj)
                    acc[ii][jj] = fmaf(a[ii], bb[jj], acc[ii][jj]);
        }
    }
    #pragma unroll
    for (int ii = 0; ii < 2; ++ii) {
        int n = n0 + ty * 2 + ii;
        if (n >= NN) continue;
        float* Erow = Ed + ((size_t)(b * NN + n)) * MP;
        #pragma unroll
        for (int off = 0; off < 3; ++off) {
            int m = tx * 4 + off * 64;
            if (m >= MP) continue;                   // off==2 && tx>=12
            float4 v;
            v.x = fast_tanh(acc[ii][off * 4 + 0]);
            v.y = fast_tanh(acc[ii][off * 4 + 1]);
            v.z = fast_tanh(acc[ii][off * 4 + 2]);
            v.w = fast_tanh(acc[ii][off * 4 + 3]);
            *reinterpret_cast<float4*>(Erow + m) = v;
        }
    }
}

// ---------------------------------------------------------------------------
// K3: scores[n][k] = relu( dot_m(Ed[b,n,:], Ed[b,k,:]) / sqrt(C) ), row
// softmax over k<170, then the batch-mean is accumulated DIRECTLY into
// Pm[n][k] via atomicAdd(prob/128) -- P is never materialized (saves ~30 MB
// of traffic + a kernel vs the R3 structure).
// Block = (b, 32-row tile): grid (6,128)=768 = 3 blocks/CU.
// Single LDS buffer Bs[mm][k] (k<192, zeros past 170) serves BOTH operand
// fragments. Softmax fully in-register via 16-lane shfl_xor reductions.
// ---------------------------------------------------------------------------
__global__ __launch_bounds__(256) void k3_scores(const float* __restrict__ Ed,
                                                 float* __restrict__ Pm) {
    const int b = blockIdx.y, r0 = blockIdx.x * 32;
    const int t = threadIdx.x, tx = t & 15, ty = t >> 4;
    __shared__ __align__(16) float Bs[16][BSROW];   // [mm][k], 12.5 KB
    const float* __restrict__ Edb = Ed + (size_t)b * NN * MP;

    float acc[2][12] = {};
    for (int mc = 0; mc < MP; mc += 16) {
        __syncthreads();
        #pragma unroll
        for (int it = 0; it < 3; ++it) {             // 768 float4: k<192 x 4 quads
            int idx = t + it * 256;
            int k = idx >> 2, mq = idx & 3;
            float4 v = make_float4(0.f, 0.f, 0.f, 0.f);
            if (k < NN)
                v = *reinterpret_cast<const float4*>(Edb + (size_t)k * MP + mc + mq * 4);
            Bs[mq * 4 + 0][k] = v.x;                 // transposed scalar writes;
            Bs[mq * 4 + 1][k] = v.y;                 // consecutive k -> banks
            Bs[mq * 4 + 2][k] = v.z;                 // spread, conflict-free
            Bs[mq * 4 + 3][k] = v.w;
        }
        __syncthreads();
        #pragma unroll
        for (int mm = 0; mm < 16; ++mm) {
            float2 av = *reinterpret_cast<const float2*>(&Bs[mm][r0 + ty * 2]);
            float a[2] = {av.x, av.y};
            float bb[12];
            #pragma unroll
            for (int off = 0; off < 3; ++off) {
                float4 bv = *reinterpret_cast<const float4*>(&Bs[mm][tx * 4 + off * 64]);
                bb[off * 4 + 0] = bv.x; bb[off * 4 + 1] = bv.y;
                bb[off * 4 + 2] = bv.z; bb[off * 4 + 3] = bv.w;
            }
            #pragma unroll
            for (int ii = 0; ii < 2; ++ii)
                #pragma unroll
                for (int jj = 0; jj < 12; ++jj)
                    acc[ii][jj] = fmaf(a[ii], bb[jj], acc[ii][jj]);
        }
    }

    // In-register softmax + atomic mean-accumulate.
    const float scale = 0.08838834764831845f;        // 1/sqrt(128)
    #pragma unroll
    for (int ii = 0; ii < 2; ++ii) {
        int n = r0 + ty * 2 + ii;
        float vv[12];
        float mx = -1.f;                             // valid scores are >= 0
        #pragma unroll
        for (int jj = 0; jj < 12; ++jj) {
            int k = tx * 4 + (jj & 3) + (jj >> 2) * 64;
            float v = fmaxf(acc[ii][jj] * scale, 0.f);
            vv[jj] = (k < NN) ? v : -1.f;
            mx = fmaxf(mx, vv[jj]);
        }
        #pragma unroll
        for (int off = 8; off; off >>= 1) mx = fmaxf(mx, __shfl_xor(mx, off, 64));
        float ex[12], sum = 0.f;
        #pragma unroll
        for (int jj = 0; jj < 12; ++jj) {
            int k = tx * 4 + (jj & 3) + (jj >> 2) * 64;
            float e = (k < NN) ? __expf(vv[jj] - mx) : 0.f;
            ex[jj] = e;
            sum += e;
        }
        #pragma unroll
        for (int off = 8; off; off >>= 1) sum += __shfl_xor(sum, off, 64);
        float inv = (1.f / 128.f) / sum;             // prob/NB in one mul
        if (n < NN) {
            float* Pr = Pm + n * NN;
            #pragma unroll
            for (int jj = 0; jj < 12; ++jj) {
                int k = tx * 4 + (jj & 3) + (jj >> 2) * 64;
                if (k < NN) atomicAdd(Pr + k, ex[jj] * inv);
            }
        }
    }
}

// ---------------------------------------------------------------------------
// K4: out[p] = ( Pm[p] > 0.5 ) ? 1 : 0   (Pm already holds the batch mean)
// ---------------------------------------------------------------------------
__global__ __launch_bounds__(256) void k4_thresh(const float* __restrict__ Pm,
                                                 float* __restrict__ out) {
    int p = blockIdx.x * 256 + threadIdx.x;
    if (p >= PM_SZ) return;
    out[p] = (Pm[p] > 0.5f) ? 1.f : 0.f;
}

// ---------------------------------------------------------------------------
// Workspace layout (floats):
//   [0, XS_SZ)                         : xs  (padded 176)   dead after K2
//   [XS_SZ, XS_SZ+ESP_SZ)              : Esp (padded 176)   dead after K2
//   [XS_SZ+ESP_SZ, +ED_SZ)             : Ed  (padded 176)   dead after K3
//   [XS_SZ+ESP_SZ+ED_SZ, +PM_SZ)       : Pm  (mean accumulator)
// Total = 27.06 MB (< the 30.64 MB used in prior passing rounds).
// ---------------------------------------------------------------------------
extern "C" void kernel_launch(void* const* d_in, const int* in_sizes, int n_in,
                              void* d_out, int out_size, void* d_ws, size_t ws_size,
                              hipStream_t stream) {
    const float* x  = (const float*)d_in[0];   // [128,128,170,12] f32
    const float* Es = (const float*)d_in[1];   // [128,170] f32
    float* out = (float*)d_out;                // [170,170] f32
    float* wsf = (float*)d_ws;

    float* xs  = wsf;
    float* Esp = wsf + XS_SZ;
    float* Ed  = wsf + XS_SZ + ESP_SZ;
    float* Pm  = wsf + XS_SZ + ESP_SZ + ED_SZ;

    k1_reduce_pad<<<11081, 256, 0, stream>>>(x, Es, xs, Esp, Pm);
    k2_embed<<<dim3(6, 128), 256, 0, stream>>>(xs, Esp, Ed);
    k3_scores<<<dim3(6, 128), 256, 0, stream>>>(Ed, Pm);
    k4_thresh<<<113, 256, 0, stream>>>(Pm, out);
}

// Round 6
// 243.744 us; speedup vs baseline: 1.2973x; 1.2973x over previous
//
#include <hip/hip_runtime.h>
#include <math.h>

// Problem constants
#define NB 128     // batch
#define NC 128     // channels
#define NN 170     // nodes
#define NT 12      // length
#define MP 176     // padded row stride (16B-aligned rows) for Esp/Ed/P
#define BSROW 196  // LDS row stride for staged tiles (196%32==4 -> bank spread)

// Workspace regions (floats)
#define ESP_SZ (NC * MP)        //    22,528
#define ED_SZ  (NB * NN * MP)   // 3,829,760
#define P_SZ   (NB * NN * MP)   // 3,829,760
#define PM_SZ  (8 * NN * NN)    //   231,200

// tanh via hw exp+rcp: ~6 VALU ops vs ~30+ for libm tanhf. rel err ~1e-6.
__device__ __forceinline__ float fast_tanh(float x) {
    float cx = fminf(fmaxf(x, -15.f), 15.f);        // avoid inf/inf
    float e  = __expf(2.f * cx);                    // v_exp_f32
    return (e - 1.f) * __builtin_amdgcn_rcpf(e + 1.f);
}

// ---------------------------------------------------------------------------
// K0: Esp = Es padded to row stride 176 (zeros in cols [170,176)).
// Tiny: 88 blocks. (Es rows are only 8B-aligned at stride 170, so K2 can't
// float4-load them directly -- pad once here instead.)
// ---------------------------------------------------------------------------
__global__ __launch_bounds__(256) void k0_pad_es(const float* __restrict__ Es,
                                                 float* __restrict__ Esp) {
    int idx = blockIdx.x * 256 + threadIdx.x;
    if (idx < ESP_SZ) {
        int c = idx / MP, m = idx % MP;
        Esp[idx] = (m < NN) ? Es[c * NN + m] : 0.f;
    }
}

// ---------------------------------------------------------------------------
// K2 (fused K1+K2): Ed[b][n][m] = tanh( sum_c (sum_t x[b][c][n][t]) * Esp[c][m] )
// xs is never materialized: the A-stage loads 12 raw floats per (c,n) from x
// (3x float4, 48B-aligned) and reduces in-register. x is read exactly once
// across the grid (disjoint n-slices per block). Saves K1's 133MB read +
// 11.5MB write + launch vs the R3 structure.
// Block = (b, 32-row tile): grid (6,128)=768 = 3 blocks/CU (12 waves/CU --
// measured better than 48-row/2-blocks, R4 post-mortem).
// Thread owns rows ty*2+{0,1}, cols tx*4 + off*64 (off<3). acc[2][12].
// ---------------------------------------------------------------------------
__global__ __launch_bounds__(256) void k2_fused(const float* __restrict__ x,
                                                const float* __restrict__ Esp,
                                                float* __restrict__ Ed) {
    const int b = blockIdx.y, n0 = blockIdx.x * 32;
    const int t = threadIdx.x, tx = t & 15, ty = t >> 4;
    __shared__ __align__(16) float As[16][36];      // [c][n], 2.3 KB
    __shared__ __align__(16) float Bs[16][BSROW];   // [c][m], 12.5 KB

    float acc[2][12] = {};
    for (int c0 = 0; c0 < NC; c0 += 16) {
        __syncthreads();
        // A-stage: 512 (c,n) groups; thread handles groups 2t, 2t+1.
        // c = t>>4, n-pair = (t&15)*2. Each group: 3 float4 from x, sum 12.
        {
            int c  = t >> 4;
            int nn = (t & 15) * 2;
            #pragma unroll
            for (int u = 0; u < 2; ++u) {
                int n = n0 + nn + u;
                float s = 0.f;
                if (n < NN) {                        // n0=160 tile: rows >=170 zero
                    const float4* p = reinterpret_cast<const float4*>(
                        x + ((size_t)((b * NC + c0 + c) * NN) + n) * NT);
                    float4 f0 = p[0], f1 = p[1], f2 = p[2];
                    s = ((f0.x + f0.y) + (f0.z + f0.w))
                      + ((f1.x + f1.y) + (f1.z + f1.w))
                      + ((f2.x + f2.y) + (f2.z + f2.w));
                }
                As[c][nn + u] = s;                   // stride-2 scalar: 2-way, free
            }
        }
        #pragma unroll
        for (int it = 0; it < 3; ++it) {             // B: 768 float4 (16c x 192m)
            int idx = t + it * 256;
            int c = idx / 48, mq = idx - c * 48;
            float4 v = make_float4(0.f, 0.f, 0.f, 0.f);
            if (mq < 44)
                v = *reinterpret_cast<const float4*>(Esp + (c0 + c) * MP + mq * 4);
            *reinterpret_cast<float4*>(&Bs[c][mq * 4]) = v;
        }
        __syncthreads();
        #pragma unroll
        for (int cc = 0; cc < 16; ++cc) {
            float2 av = *reinterpret_cast<const float2*>(&As[cc][ty * 2]);
            float a[2] = {av.x, av.y};
            float bb[12];
            #pragma unroll
            for (int off = 0; off < 3; ++off) {
                float4 bv = *reinterpret_cast<const float4*>(&Bs[cc][tx * 4 + off * 64]);
                bb[off * 4 + 0] = bv.x; bb[off * 4 + 1] = bv.y;
                bb[off * 4 + 2] = bv.z; bb[off * 4 + 3] = bv.w;
            }
            #pragma unroll
            for (int ii = 0; ii < 2; ++ii)
                #pragma unroll
                for (int jj = 0; jj < 12; ++jj)
                    acc[ii][jj] = fmaf(a[ii], bb[jj], acc[ii][jj]);
        }
    }
    #pragma unroll
    for (int ii = 0; ii < 2; ++ii) {
        int n = n0 + ty * 2 + ii;
        if (n >= NN) continue;
        float* Erow = Ed + ((size_t)(b * NN + n)) * MP;
        #pragma unroll
        for (int off = 0; off < 3; ++off) {
            int m = tx * 4 + off * 64;
            if (m >= MP) continue;                   // off==2 && tx>=12
            float4 v;
            v.x = fast_tanh(acc[ii][off * 4 + 0]);
            v.y = fast_tanh(acc[ii][off * 4 + 1]);
            v.z = fast_tanh(acc[ii][off * 4 + 2]);
            v.w = fast_tanh(acc[ii][off * 4 + 3]);
            *reinterpret_cast<float4*>(Erow + m) = v;
        }
    }
}

// ---------------------------------------------------------------------------
// K3: scores[n][k] = relu( dot_m(Ed[b,n,:], Ed[b,k,:]) / sqrt(C) ), row
// softmax over k<170, write P[b][n][k] (stride 176). R3's verified-best
// config: block = (b, 32-row tile), grid (6,128)=768 = 3 blocks/CU; single
// LDS buffer serves both operand fragments; in-register softmax via 16-lane
// shfl_xor. (Atomic-fusion variant measured 112us -- cross-XCD RMW storm;
// materializing P + K4a partial reduce is strictly faster. R5 post-mortem.)
// ---------------------------------------------------------------------------
__global__ __launch_bounds__(256) void k3_scores(const float* __restrict__ Ed,
                                                 float* __restrict__ P) {
    const int b = blockIdx.y, r0 = blockIdx.x * 32;
    const int t = threadIdx.x, tx = t & 15, ty = t >> 4;
    __shared__ __align__(16) float Bs[16][BSROW];   // [mm][k], 12.5 KB
    const float* __restrict__ Edb = Ed + (size_t)b * NN * MP;

    float acc[2][12] = {};
    for (int mc = 0; mc < MP; mc += 16) {
        __syncthreads();
        #pragma unroll
        for (int it = 0; it < 3; ++it) {             // 768 float4: k<192 x 4 quads
            int idx = t + it * 256;
            int k = idx >> 2, mq = idx & 3;
            float4 v = make_float4(0.f, 0.f, 0.f, 0.f);
            if (k < NN)
                v = *reinterpret_cast<const float4*>(Edb + (size_t)k * MP + mc + mq * 4);
            Bs[mq * 4 + 0][k] = v.x;                 // transposed scalar writes;
            Bs[mq * 4 + 1][k] = v.y;                 // consecutive k -> banks
            Bs[mq * 4 + 2][k] = v.z;                 // spread, conflict-free
            Bs[mq * 4 + 3][k] = v.w;
        }
        __syncthreads();
        #pragma unroll
        for (int mm = 0; mm < 16; ++mm) {
            float2 av = *reinterpret_cast<const float2*>(&Bs[mm][r0 + ty * 2]);
            float a[2] = {av.x, av.y};
            float bb[12];
            #pragma unroll
            for (int off = 0; off < 3; ++off) {
                float4 bv = *reinterpret_cast<const float4*>(&Bs[mm][tx * 4 + off * 64]);
                bb[off * 4 + 0] = bv.x; bb[off * 4 + 1] = bv.y;
                bb[off * 4 + 2] = bv.z; bb[off * 4 + 3] = bv.w;
            }
            #pragma unroll
            for (int ii = 0; ii < 2; ++ii)
                #pragma unroll
                for (int jj = 0; jj < 12; ++jj)
                    acc[ii][jj] = fmaf(a[ii], bb[jj], acc[ii][jj]);
        }
    }

    // In-register softmax. Thread's cols: k = tx*4 + (jj&3) + (jj>>2)*64.
    const float scale = 0.08838834764831845f;        // 1/sqrt(128)
    #pragma unroll
    for (int ii = 0; ii < 2; ++ii) {
        int n = r0 + ty * 2 + ii;
        float vv[12];
        float mx = -1.f;                             // valid scores are >= 0
        #pragma unroll
        for (int jj = 0; jj < 12; ++jj) {
            int k = tx * 4 + (jj & 3) + (jj >> 2) * 64;
            float v = fmaxf(acc[ii][jj] * scale, 0.f);
            vv[jj] = (k < NN) ? v : -1.f;
            mx = fmaxf(mx, vv[jj]);
        }
        #pragma unroll
        for (int off = 8; off; off >>= 1) mx = fmaxf(mx, __shfl_xor(mx, off, 64));
        float ex[12], sum = 0.f;
        #pragma unroll
        for (int jj = 0; jj < 12; ++jj) {
            int k = tx * 4 + (jj & 3) + (jj >> 2) * 64;
            float e = (k < NN) ? __expf(vv[jj] - mx) : 0.f;
            ex[jj] = e;
            sum += e;
        }
        #pragma unroll
        for (int off = 8; off; off >>= 1) sum += __shfl_xor(sum, off, 64);
        float inv = 1.f / sum;
        if (n < NN) {
            float* Pr = P + ((size_t)(b * NN + n)) * MP;
            #pragma unroll
            for (int off = 0; off < 3; ++off) {
                int k = tx * 4 + off * 64;
                if (k >= MP) continue;               // off==2 && tx>=12
                float4 v;                            // cols >=170 are pad: e==0
                v.x = ex[off * 4 + 0] * inv; v.y = ex[off * 4 + 1] * inv;
                v.z = ex[off * 4 + 2] * inv; v.w = ex[off * 4 + 3] * inv;
                *reinterpret_cast<float4*>(Pr + k) = v;
            }
        }
    }
}

// ---------------------------------------------------------------------------
// K4a: batch-partial means -- grid (113, 8); block y sums 16 batches.
// K4b: combine 8 partials + threshold.
// ---------------------------------------------------------------------------
__global__ __launch_bounds__(256) void k4a_partial(const float* __restrict__ P,
                                                   float* __restrict__ Pm) {
    int p = blockIdx.x * 256 + threadIdx.x;
    if (p >= NN * NN) return;
    int n = p / NN, k = p - n * NN;
    const float* base = P + (size_t)blockIdx.y * 16 * NN * MP + (size_t)n * MP + k;
    float s = 0.f;
    #pragma unroll
    for (int b = 0; b < 16; ++b) s += base[(size_t)b * NN * MP];
    Pm[blockIdx.y * (NN * NN) + p] = s;
}

__global__ __launch_bounds__(256) void k4b_thresh(const float* __restrict__ Pm,
                                                  float* __restrict__ out) {
    int p = blockIdx.x * 256 + threadIdx.x;
    if (p >= NN * NN) return;
    float s = 0.f;
    #pragma unroll
    for (int g = 0; g < 8; ++g) s += Pm[g * (NN * NN) + p];
    out[p] = (s * (1.f / 128.f) > 0.5f) ? 1.f : 0.f;
}

// ---------------------------------------------------------------------------
// Workspace layout (floats):
//   [0, ESP_SZ)        : Esp (padded 176)   dead after K2
//   [+, +ED_SZ)        : Ed  (padded 176)   dead after K3
//   [+, +P_SZ)         : P   (padded 176)   dead after K4a
//   [+, +PM_SZ)        : Pm  (8 batch-partials)
// Total = 31.65 MB.
// ---------------------------------------------------------------------------
extern "C" void kernel_launch(void* const* d_in, const int* in_sizes, int n_in,
                              void* d_out, int out_size, void* d_ws, size_t ws_size,
                              hipStream_t stream) {
    const float* x  = (const float*)d_in[0];   // [128,128,170,12] f32
    const float* Es = (const float*)d_in[1];   // [128,170] f32
    float* out = (float*)d_out;                // [170,170] f32
    float* wsf = (float*)d_ws;

    float* Esp = wsf;
    float* Ed  = wsf + ESP_SZ;
    float* P   = wsf + ESP_SZ + ED_SZ;
    float* Pm  = wsf + ESP_SZ + ED_SZ + P_SZ;

    k0_pad_es<<<88, 256, 0, stream>>>(Es, Esp);
    k2_fused<<<dim3(6, 128), 256, 0, stream>>>(x, Esp, Ed);
    k3_scores<<<dim3(6, 128), 256, 0, stream>>>(Ed, P);
    k4a_partial<<<dim3(113, 8), 256, 0, stream>>>(P, Pm);
    k4b_thresh<<<113, 256, 0, stream>>>(Pm, out);
}

// Round 8
// 234.656 us; speedup vs baseline: 1.3475x; 1.0387x over previous
//
#include <hip/hip_runtime.h>
#include <math.h>

// Problem constants
#define NB 128     // batch
#define NC 128     // channels
#define NN 170     // nodes
#define NT 12      // length
#define MP 176     // padded row stride (16B-aligned rows) for Esp/Ed/P
#define BSROW 196  // LDS row stride for K2 staged tiles

// Workspace regions (floats)
#define ESP_SZ (NC * MP)        //    22,528
#define ED_SZ  (NB * NN * MP)   // 3,829,760
#define P_SZ   (NB * NN * MP)   // 3,829,760
#define PM_SZ  (8 * NN * NN)    //   231,200

// MFMA fragment / accumulator types (16x16x32 f16: 8 halfs per operand lane)
typedef _Float16 h8 __attribute__((ext_vector_type(8)));
typedef _Float16 h4 __attribute__((ext_vector_type(4)));
typedef __fp16   g2 __attribute__((ext_vector_type(2)));  // cvt_pkrtz return type
typedef float    f4 __attribute__((ext_vector_type(4)));

// tanh via hw exp+rcp: ~6 VALU ops vs ~30+ for libm tanhf. rel err ~1e-6.
__device__ __forceinline__ float fast_tanh(float x) {
    float cx = fminf(fmaxf(x, -15.f), 15.f);        // avoid inf/inf
    float e  = __expf(2.f * cx);                    // v_exp_f32
    return (e - 1.f) * __builtin_amdgcn_rcpf(e + 1.f);
}

// ---------------------------------------------------------------------------
// K0: Esp = Es padded to row stride 176 (zeros in cols [170,176)).
// ---------------------------------------------------------------------------
__global__ __launch_bounds__(256) void k0_pad_es(const float* __restrict__ Es,
                                                 float* __restrict__ Esp) {
    int idx = blockIdx.x * 256 + threadIdx.x;
    if (idx < ESP_SZ) {
        int c = idx / MP, m = idx % MP;
        Esp[idx] = (m < NN) ? Es[c * NN + m] : 0.f;
    }
}

// ---------------------------------------------------------------------------
// K2 (fused K1+K2): Ed[b][n][m] = tanh( sum_c (sum_t x[b][c][n][t]) * Esp[c][m] )
// HBM-bound at the 133 MB x-read floor (~22us); fp32 VALU GEMM, unchanged
// from R6 (passing, best config: 32-row tiles, grid (6,128)=3 blocks/CU).
// ---------------------------------------------------------------------------
__global__ __launch_bounds__(256) void k2_fused(const float* __restrict__ x,
                                                const float* __restrict__ Esp,
                                                float* __restrict__ Ed) {
    const int b = blockIdx.y, n0 = blockIdx.x * 32;
    const int t = threadIdx.x, tx = t & 15, ty = t >> 4;
    __shared__ __align__(16) float As[16][36];      // [c][n], 2.3 KB
    __shared__ __align__(16) float Bs[16][BSROW];   // [c][m], 12.5 KB

    float acc[2][12] = {};
    for (int c0 = 0; c0 < NC; c0 += 16) {
        __syncthreads();
        {   // A-stage: 512 (c,n) groups; thread handles groups 2t, 2t+1.
            int c  = t >> 4;
            int nn = (t & 15) * 2;
            #pragma unroll
            for (int u = 0; u < 2; ++u) {
                int n = n0 + nn + u;
                float s = 0.f;
                if (n < NN) {
                    const float4* p = reinterpret_cast<const float4*>(
                        x + ((size_t)((b * NC + c0 + c) * NN) + n) * NT);
                    float4 f0 = p[0], f1 = p[1], f2 = p[2];
                    s = ((f0.x + f0.y) + (f0.z + f0.w))
                      + ((f1.x + f1.y) + (f1.z + f1.w))
                      + ((f2.x + f2.y) + (f2.z + f2.w));
                }
                As[c][nn + u] = s;
            }
        }
        #pragma unroll
        for (int it = 0; it < 3; ++it) {             // B: 768 float4 (16c x 192m)
            int idx = t + it * 256;
            int c = idx / 48, mq = idx - c * 48;
            float4 v = make_float4(0.f, 0.f, 0.f, 0.f);
            if (mq < 44)
                v = *reinterpret_cast<const float4*>(Esp + (c0 + c) * MP + mq * 4);
            *reinterpret_cast<float4*>(&Bs[c][mq * 4]) = v;
        }
        __syncthreads();
        #pragma unroll
        for (int cc = 0; cc < 16; ++cc) {
            float2 av = *reinterpret_cast<const float2*>(&As[cc][ty * 2]);
            float a[2] = {av.x, av.y};
            float bb[12];
            #pragma unroll
            for (int off = 0; off < 3; ++off) {
                float4 bv = *reinterpret_cast<const float4*>(&Bs[cc][tx * 4 + off * 64]);
                bb[off * 4 + 0] = bv.x; bb[off * 4 + 1] = bv.y;
                bb[off * 4 + 2] = bv.z; bb[off * 4 + 3] = bv.w;
            }
            #pragma unroll
            for (int ii = 0; ii < 2; ++ii)
                #pragma unroll
                for (int jj = 0; jj < 12; ++jj)
                    acc[ii][jj] = fmaf(a[ii], bb[jj], acc[ii][jj]);
        }
    }
    #pragma unroll
    for (int ii = 0; ii < 2; ++ii) {
        int n = n0 + ty * 2 + ii;
        if (n >= NN) continue;
        float* Erow = Ed + ((size_t)(b * NN + n)) * MP;
        #pragma unroll
        for (int off = 0; off < 3; ++off) {
            int m = tx * 4 + off * 64;
            if (m >= MP) continue;
            float4 v;
            v.x = fast_tanh(acc[ii][off * 4 + 0]);
            v.y = fast_tanh(acc[ii][off * 4 + 1]);
            v.z = fast_tanh(acc[ii][off * 4 + 2]);
            v.w = fast_tanh(acc[ii][off * 4 + 3]);
            *reinterpret_cast<float4*>(Erow + m) = v;
        }
    }
}

// ---------------------------------------------------------------------------
// K3 (MFMA): scores = relu(Ed[b]·Ed[b]^T / sqrt(C)), row softmax, write P.
// R6 post-mortem: the fp32 VALU version was LDS-PIPE bound (~57KB LDS reads
// per wave per chunk through the per-CU 85B/cyc pipe => ~38us). MFMA frags
// consume ~9x less LDS per FLOP.
// Structure: block = (b, 32-row tile), grid (6,128)=768 = 3 blocks/CU.
//  - Per 32-wide K-chunk (6 chunks, K=192 padded): stage Ed[b] rows 0..191,
//    cols [mc,mc+32) into LDS as f16 (zeros for rows>=170 / cols>=176).
//  - C = A*B^T pattern (m97-family, HW-verified): A-frag = rows r0+rt*16+l15,
//    B-frag = rows ct*16+l15, SAME per-lane layout (8 contiguous k at
//    quad*8), only base row differs. 4 waves x (2 row-tiles x 3 col-tiles),
//    6 mfma_f32_16x16x32_f16 per wave per chunk.
//  - D layout (m89-verified): col=lane&15, row=quad*4+reg.
//  - Scores -> LDS Sc[32][204], then R2-proven per-wave softmax (wave w owns
//    rows w*8..w*8+7; lane covers k=lane,+64,+128 masked at 170).
// f16 (not bf16): 2^-11 mantissa => prob perturbation <1%; binary output
// margins (R1 diagnostics) are far larger.
// ---------------------------------------------------------------------------
__global__ __launch_bounds__(256) void k3_scores_mfma(const float* __restrict__ Ed,
                                                      float* __restrict__ P) {
    const int b = blockIdx.y, r0 = blockIdx.x * 32;
    const int t = threadIdx.x;
    const int lane = t & 63, wave = t >> 6;
    const int l15 = lane & 15, quad = lane >> 4;

    __shared__ __align__(16) _Float16 Eh[192 * 40];  // [k-row][chunk k], stride 40 halfs (80B)
    __shared__ __align__(16) float    Sc[32 * 204];  // [n_local][k], stride 204

    const float* __restrict__ Edb = Ed + (size_t)b * NN * MP;

    f4 acc[2][3] = {};                               // 2 row-tiles x 3 col-tiles
    for (int mc = 0; mc < 192; mc += 32) {
        __syncthreads();
        // Stage: 192 rows x 8 quad-cols = 1536 float4 slots -> f16.
        #pragma unroll
        for (int it = 0; it < 6; ++it) {
            int idx = t + it * 256;                  // [0,1536)
            int row = idx >> 3, q = idx & 7;
            float4 v = make_float4(0.f, 0.f, 0.f, 0.f);
            int col = mc + q * 4;
            if (row < NN && col < MP)                // col mult of 4; col<176 => +3 in-bounds
                v = *reinterpret_cast<const float4*>(Edb + (size_t)row * MP + col);
            g2 lo = __builtin_amdgcn_cvt_pkrtz(v.x, v.y);  // v_cvt_pkrtz_f16_f32
            g2 hi = __builtin_amdgcn_cvt_pkrtz(v.z, v.w);
            h4 h;
            h[0] = (_Float16)lo[0]; h[1] = (_Float16)lo[1];
            h[2] = (_Float16)hi[0]; h[3] = (_Float16)hi[1];
            *reinterpret_cast<h4*>(&Eh[row * 40 + q * 4]) = h;   // 8B ds_write
        }
        __syncthreads();
        const int ko = quad * 8;                     // k-offset within chunk
        h8 a0 = *reinterpret_cast<const h8*>(&Eh[(r0 + l15) * 40 + ko]);
        h8 a1 = *reinterpret_cast<const h8*>(&Eh[(r0 + 16 + l15) * 40 + ko]);
        #pragma unroll
        for (int ci = 0; ci < 3; ++ci) {
            int kc = (wave * 3 + ci) * 16 + l15;     // B base row (= score col)
            h8 bf = *reinterpret_cast<const h8*>(&Eh[kc * 40 + ko]);
            acc[0][ci] = __builtin_amdgcn_mfma_f32_16x16x32_f16(a0, bf, acc[0][ci], 0, 0, 0);
            acc[1][ci] = __builtin_amdgcn_mfma_f32_16x16x32_f16(a1, bf, acc[1][ci], 0, 0, 0);
        }
    }

    // Scatter scaled+relu scores to Sc.
    const float scale = 0.08838834764831845f;        // 1/sqrt(128)
    #pragma unroll
    for (int rt = 0; rt < 2; ++rt)
        #pragma unroll
        for (int ci = 0; ci < 3; ++ci) {
            int col = (wave * 3 + ci) * 16 + l15;
            #pragma unroll
            for (int reg = 0; reg < 4; ++reg) {
                int rloc = rt * 16 + quad * 4 + reg;
                Sc[rloc * 204 + col] = fmaxf(acc[rt][ci][reg] * scale, 0.f);
            }
        }
    __syncthreads();

    // Softmax: wave w owns rows w*8 .. w*8+7. relu => valid values >= 0.
    for (int rr = 0; rr < 8; ++rr) {
        int r = wave * 8 + rr;
        int n = r0 + r;
        if (n >= NN) continue;                       // uniform per iteration
        float v0 = Sc[r * 204 + lane];
        float v1 = Sc[r * 204 + lane + 64];
        int  k2i = lane + 128;
        bool has2 = (k2i < NN);
        float v2 = has2 ? Sc[r * 204 + k2i] : -1.f;
        float m = fmaxf(fmaxf(v0, v1), v2);
        #pragma unroll
        for (int off = 32; off; off >>= 1) m = fmaxf(m, __shfl_xor(m, off, 64));
        float e0 = __expf(v0 - m);
        float e1 = __expf(v1 - m);
        float e2 = has2 ? __expf(v2 - m) : 0.f;
        float s = e0 + e1 + e2;
        #pragma unroll
        for (int off = 32; off; off >>= 1) s += __shfl_xor(s, off, 64);
        float inv = 1.f / s;
        float* Pr = P + ((size_t)(b * NN + n)) * MP;
        Pr[lane]      = e0 * inv;
        Pr[lane + 64] = e1 * inv;
        if (has2) Pr[k2i] = e2 * inv;
    }
}

// ---------------------------------------------------------------------------
// K4a: batch-partial means -- grid (113, 8); block y sums 16 batches.
// K4b: combine 8 partials + threshold. (K4 reads only k<170 per row, so P's
// pad cols may stay unwritten.)
// ---------------------------------------------------------------------------
__global__ __launch_bounds__(256) void k4a_partial(const float* __restrict__ P,
                                                   float* __restrict__ Pm) {
    int p = blockIdx.x * 256 + threadIdx.x;
    if (p >= NN * NN) return;
    int n = p / NN, k = p - n * NN;
    const float* base = P + (size_t)blockIdx.y * 16 * NN * MP + (size_t)n * MP + k;
    float s = 0.f;
    #pragma unroll
    for (int b = 0; b < 16; ++b) s += base[(size_t)b * NN * MP];
    Pm[blockIdx.y * (NN * NN) + p] = s;
}

__global__ __launch_bounds__(256) void k4b_thresh(const float* __restrict__ Pm,
                                                  float* __restrict__ out) {
    int p = blockIdx.x * 256 + threadIdx.x;
    if (p >= NN * NN) return;
    float s = 0.f;
    #pragma unroll
    for (int g = 0; g < 8; ++g) s += Pm[g * (NN * NN) + p];
    out[p] = (s * (1.f / 128.f) > 0.5f) ? 1.f : 0.f;
}

// ---------------------------------------------------------------------------
// Workspace layout (floats):
//   [0, ESP_SZ)        : Esp (padded 176)   dead after K2
//   [+, +ED_SZ)        : Ed  (padded 176)   dead after K3
//   [+, +P_SZ)         : P   (padded 176)   dead after K4a
//   [+, +PM_SZ)        : Pm  (8 batch-partials)
// Total = 31.65 MB.
// ---------------------------------------------------------------------------
extern "C" void kernel_launch(void* const* d_in, const int* in_sizes, int n_in,
                              void* d_out, int out_size, void* d_ws, size_t ws_size,
                              hipStream_t stream) {
    const float* x  = (const float*)d_in[0];   // [128,128,170,12] f32
    const float* Es = (const float*)d_in[1];   // [128,170] f32
    float* out = (float*)d_out;                // [170,170] f32
    float* wsf = (float*)d_ws;

    float* Esp = wsf;
    float* Ed  = wsf + ESP_SZ;
    float* P   = wsf + ESP_SZ + ED_SZ;
    float* Pm  = wsf + ESP_SZ + ED_SZ + P_SZ;

    k0_pad_es<<<88, 256, 0, stream>>>(Es, Esp);
    k2_fused<<<dim3(6, 128), 256, 0, stream>>>(x, Esp, Ed);
    k3_scores_mfma<<<dim3(6, 128), 256, 0, stream>>>(Ed, P);
    k4a_partial<<<dim3(113, 8), 256, 0, stream>>>(P, Pm);
    k4b_thresh<<<113, 256, 0, stream>>>(Pm, out);
}